// Round 1
// baseline (109.699 us; speedup 1.0000x reference)
//
#include <hip/hip_runtime.h>

// MLP: 64 × (Linear(5,5)+ReLU) then Linear(5,1), BATCH = 1048576 rows.
// fp32 VALU issue-bound. R9: row-fused ReLU + rolled layer loop.
//
// R8 post-mortem: VALUBusy ~100% but dur 51 µs vs ~39 µs instruction floor
// at sustained VALU clock — and VGPR_Count=32. The R8 source computed all
// 20 accumulators a[4][5] before the ReLU pass, so the clean schedule needs
// W(32)+h(20)+acc(20) live; the allocator instead contorted to 32 VGPRs by
// sinking ds_reads per-use + repack movs ≈ +30 VALU/layer = the 25-30% gap.
//
// Fix: (1) fuse ReLU per row — acc live range is 5, peak pressure
// W(32)+h(20)+acc(5)+misc ≈ 60 regs, comfortably under the 128-reg budget
// of __launch_bounds__(256,4); (2) roll the layer loop (unroll 2) for a
// regular ~250-instr body that still lets layer l+1's ds_reads pipeline
// into layer l's FMAs; (3) sched_barrier(0) after the 8 ds_read_b128 so
// the scheduler cannot re-sink them into the compute. FMA chains are
// i-outer/j-inner: 5 independent chains per row cover FMA latency.
// Ideal per layer per thread: 8 DS + 120 VALU (4×25 v_fma, bias as first
// fma's VOP3 addend; 4×5 v_max).

#define MLP_DEPTH 64
#define MLP_D 5
#define ROWS 4

// LDS layout: layer l at sw[l*32]: k<25 -> W[j*5+i] (k=j*5+i), 25..29 -> b[j],
// 30..31 pad. Then at sw[2048]: W_out[0..4], b_out, pad, pad. Total 2056.
#define LDS_N 2056

__global__ __launch_bounds__(256, 4) void MLP_89687507075104_kernel(
    const float* __restrict__ x,      // [n, 5]
    const float* __restrict__ Ws,     // [64, 5, 5]
    const float* __restrict__ bs,     // [64, 5]
    const float* __restrict__ W_out,  // [1, 5]
    const float* __restrict__ b_out,  // [1]
    float* __restrict__ out,          // [n]
    int n)
{
    __shared__ float sw[LDS_N];
    for (int idx = threadIdx.x; idx < LDS_N; idx += 256) {
        float v;
        if (idx < MLP_DEPTH * 32) {
            const int l = idx >> 5, k = idx & 31;
            v = (k < 25) ? Ws[l * 25 + k]
              : (k < 30) ? bs[l * MLP_D + (k - 25)]
              : 0.0f;
        } else {
            const int k = idx - MLP_DEPTH * 32;
            v = (k < MLP_D) ? W_out[k] : (k == MLP_D) ? b_out[0] : 0.0f;
        }
        sw[idx] = v;
    }
    __syncthreads();

    const int t = blockIdx.x * blockDim.x + threadIdx.x;
    const long row0 = (long)t * ROWS;
    if (row0 >= n) return;

    // rows row0..row0+3 = 20 contiguous floats (80 B, 16B-aligned).
    const float4* xp = reinterpret_cast<const float4*>(x + row0 * MLP_D);
    const float4 q0 = xp[0], q1 = xp[1], q2 = xp[2], q3 = xp[3], q4 = xp[4];
    float h[ROWS][MLP_D];
    h[0][0]=q0.x; h[0][1]=q0.y; h[0][2]=q0.z; h[0][3]=q0.w; h[0][4]=q1.x;
    h[1][0]=q1.y; h[1][1]=q1.z; h[1][2]=q1.w; h[1][3]=q2.x; h[1][4]=q2.y;
    h[2][0]=q2.z; h[2][1]=q2.w; h[2][2]=q3.x; h[2][3]=q3.y; h[2][4]=q3.z;
    h[3][0]=q3.w; h[3][1]=q4.x; h[3][2]=q4.y; h[3][3]=q4.z; h[3][4]=q4.w;

#pragma unroll 2
    for (int l = 0; l < MLP_DEPTH; ++l) {
        // 8× ds_read_b128, broadcast (all lanes same address), offsets are
        // immediates off one per-layer base -> no per-read address VALU.
        const float4* wq = reinterpret_cast<const float4*>(&sw[l * 32]);
        float W[32];
#pragma unroll
        for (int m = 0; m < 8; ++m) {
            const float4 c = wq[m];
            W[4*m+0] = c.x; W[4*m+1] = c.y; W[4*m+2] = c.z; W[4*m+3] = c.w;
        }
        // Pin the loads ahead of the compute: the scheduler may not re-sink
        // them per-use (the R8 32-VGPR contortion). Layer l+1's loads may
        // still hoist down into this layer's FMAs (they sit after this
        // barrier in program order).
        __builtin_amdgcn_sched_barrier(0);

        // Row-fused compute+ReLU: acc live range is one row (5 regs).
        // i-outer/j-inner => 5 independent FMA chains cover VALU latency.
#pragma unroll
        for (int r = 0; r < ROWS; ++r) {
            float acc[MLP_D];
#pragma unroll
            for (int j = 0; j < MLP_D; ++j)
                acc[j] = fmaf(h[r][0], W[j * MLP_D + 0], W[25 + j]);
#pragma unroll
            for (int i = 1; i < MLP_D; ++i)
#pragma unroll
                for (int j = 0; j < MLP_D; ++j)
                    acc[j] = fmaf(h[r][i], W[j * MLP_D + i], acc[j]);
#pragma unroll
            for (int j = 0; j < MLP_D; ++j)
                h[r][j] = fmaxf(acc[j], 0.0f);
        }
    }

    // Output layer: Linear(5,1).
    const float4* oq = reinterpret_cast<const float4*>(&sw[MLP_DEPTH * 32]);
    const float4 c0 = oq[0], c1 = oq[1];
    const float wo0 = c0.x, wo1 = c0.y, wo2 = c0.z, wo3 = c0.w;
    const float wo4 = c1.x, bo = c1.y;
    float4 ov;
    float o[ROWS];
#pragma unroll
    for (int r = 0; r < ROWS; ++r) {
        float acc = fmaf(h[r][0], wo0, bo);
        acc = fmaf(h[r][1], wo1, acc);
        acc = fmaf(h[r][2], wo2, acc);
        acc = fmaf(h[r][3], wo3, acc);
        acc = fmaf(h[r][4], wo4, acc);
        o[r] = acc;
    }
    ov.x = o[0]; ov.y = o[1]; ov.z = o[2]; ov.w = o[3];
    *reinterpret_cast<float4*>(out + row0) = ov;
}

extern "C" void kernel_launch(void* const* d_in, const int* in_sizes, int n_in,
                              void* d_out, int out_size, void* d_ws, size_t ws_size,
                              hipStream_t stream) {
    const float* x     = (const float*)d_in[0];
    const float* Ws    = (const float*)d_in[1];
    const float* bs    = (const float*)d_in[2];
    const float* W_out = (const float*)d_in[3];
    const float* b_out = (const float*)d_in[4];
    float* out = (float*)d_out;

    const int n = in_sizes[0] / MLP_D;  // batch rows (1048576)
    const int block = 256;
    const int threads_needed = (n + ROWS - 1) / ROWS;
    const int grid = (threads_needed + block - 1) / block;  // 1024
    MLP_89687507075104_kernel<<<grid, block, 0, stream>>>(
        x, Ws, bs, W_out, b_out, out, n);
}